// Round 8
// baseline (533.398 us; speedup 1.0000x reference)
//
#include <hip/hip_runtime.h>
#include <hip/hip_bf16.h>
#include <hip/hip_cooperative_groups.h>

namespace cg = cooperative_groups;

#define D 128
typedef __hip_bfloat16 bf16;
typedef __attribute__((ext_vector_type(8))) short short8;
typedef __attribute__((ext_vector_type(4))) float float4v;

static __device__ __forceinline__ float bf2f(bf16 v) { return __bfloat162float(v); }
static __device__ __forceinline__ unsigned short f_to_u16bf(float f) {
    unsigned u = __float_as_uint(f);
    return (unsigned short)((u + 0x7FFFu + ((u >> 16) & 1u)) >> 16);  // RNE
}
// dtype-adaptive float load (ff=1: f32 storage, ff=0: bf16 storage)
static __device__ __forceinline__ float ldf(const void* p, long i, int ff) {
    return ff ? ((const float*)p)[i] : bf2f(((const bf16*)p)[i]);
}

// block-consistent dtype detectors (fixed sample windows -> all blocks agree)
static __device__ int detect_ff_block(const void* emb_raw) {
    const unsigned short* u = (const unsigned short*)emb_raw;
    int bad = 0;
    for (int i = threadIdx.x; i < 1024; i += blockDim.x) {
        float f = __uint_as_float((unsigned)u[i] << 16);
        if (!(fabsf(f) <= 100.f)) bad = 1;
    }
    __shared__ int sh_ff;
    if (threadIdx.x == 0) sh_ff = 0;
    __syncthreads();
    if (bad) atomicOr(&sh_ff, 1);
    __syncthreads();
    return sh_ff;  // 1 = f32
}
static __device__ int detect_fi_block(const int* eix) {
    int nz = 0;
    for (int i = threadIdx.x; i < 256; i += blockDim.x)
        if (eix[2 * i + 1] != 0) nz = 1;
    __shared__ int sh_fi;
    if (threadIdx.x == 0) sh_fi = 0;
    __syncthreads();
    if (nz) atomicOr(&sh_fi, 1);
    __syncthreads();
    return sh_fi ? 0 : 1;  // 1 = int64
}

// ---------------- K1: fused prep ----------------
// blocks 0..18: convert param tensors to f32
// blocks 19..82: layer-1 vocab tables (2 rows each) from RAW inputs
// blocks 83/84: transpose+bf16 W2l/W2r into B-operand layout [n][k]
// block 0 also publishes flags to ws
#define NCV 19
struct CvArgs { const void* s[NCV]; float* d[NCV]; int n[NCV]; };

__global__ void __launch_bounds__(256) k_prep(
    CvArgs a, const int* __restrict__ eix,
    float* __restrict__ EWl, float* __restrict__ EWr,
    unsigned short* __restrict__ w2lT, unsigned short* __restrict__ w2rT,
    int* __restrict__ flagf_out, int* __restrict__ flagi_out) {
    int ff = detect_ff_block(a.s[0]);
    int b = blockIdx.x;
    if (b == 0 && threadIdx.x == 0) {
        *flagf_out = ff;
    }
    if (b == 0) {
        int fi = detect_fi_block(eix);
        if (threadIdx.x == 0) *flagi_out = fi;
    }
    if (b < 19) {
        const void* sp = a.s[b];
        float* dp = a.d[b];
        int m = a.n[b];
        for (int i = threadIdx.x; i < m; i += 256) dp[i] = ldf(sp, i, ff);
    } else if (b < 83) {
        // vocab tables: rows rb, rb+1
        int rb = (b - 19) * 2;
        int half = threadIdx.x >> 7;
        int c = threadIdx.x & 127;
        int r = rb + half;
        __shared__ float er[2][D];
        er[half][c] = ldf(a.s[0], (long)r * D + c, ff);
        __syncthreads();
        float al = ldf(a.s[2], c, ff), ar = ldf(a.s[4], c, ff);
        for (int k = 0; k < D; ++k) {
            float e = er[half][k];
            al += e * ldf(a.s[1], (long)k * D + c, ff);
            ar += e * ldf(a.s[3], (long)k * D + c, ff);
        }
        EWl[r * D + c] = al;
        EWr[r * D + c] = ar;
    } else {
        // W2 transpose to [n][k] bf16
        const void* src = (b == 83) ? a.s[10] : a.s[12];
        unsigned short* dst = (b == 83) ? w2lT : w2rT;
        for (int idx = threadIdx.x; idx < D * D; idx += 256) {
            int nn = idx >> 7, kk = idx & 127;
            dst[idx] = f_to_u16bf(ldf(src, (long)kk * D + nn, ff));
        }
    }
}

// ---------------- K2: cooperative CSR build (zero+hist+ewsum+scan+scatter) ----------------
__global__ void __launch_bounds__(256) k_csr(
    const int* __restrict__ eix, const void* __restrict__ ewp, int E, int n,
    const int* __restrict__ flagf, const int* __restrict__ flagi,
    int* __restrict__ counts /* then cursor */, int* __restrict__ offs,
    int* __restrict__ bsum, unsigned* __restrict__ csr, float* __restrict__ ew_sum) {
    cg::grid_group g = cg::this_grid();
    int ff = *flagf, fi = *flagi;
    int tid = blockIdx.x * blockDim.x + threadIdx.x;
    int nth = gridDim.x * blockDim.x;
    __shared__ int sh[256];

    // phase 0: zero
    for (int i = tid; i < n; i += nth) counts[i] = 0;
    if (tid == 0) *ew_sum = 0.f;
    g.sync();

    // phase 1: histogram + edge-weight sum
    float ws_ = 0.f;
    for (int e = tid; e < E; e += nth) {
        int d = fi ? eix[2 * (E + e)] : eix[E + e];
        atomicAdd(&counts[d], 1);
        ws_ += ff ? ((const float*)ewp)[e] : bf2f(((const bf16*)ewp)[e]);
    }
    for (int o = 32; o > 0; o >>= 1) ws_ += __shfl_down(ws_, o, 64);
    if ((threadIdx.x & 63) == 0) atomicAdd(ew_sum, ws_);
    g.sync();

    // phase 2: per-chunk exclusive scan (chunks of 256 covering 0..n)
    int nch = (n + 1 + 255) >> 8;
    if (blockIdx.x < nch) {
        int t = threadIdx.x;
        int i = blockIdx.x * 256 + t;
        int val = (i < n) ? counts[i] : 0;
        sh[t] = val;
        __syncthreads();
        for (int o = 1; o < 256; o <<= 1) {
            int x = (t >= o) ? sh[t - o] : 0;
            __syncthreads();
            sh[t] += x;
            __syncthreads();
        }
        if (i <= n) offs[i] = sh[t] - val;
        if (t == 255) bsum[blockIdx.x] = sh[255];
    }
    g.sync();

    // phase 3: scan chunk totals (block 0; nch <= 256)
    if (blockIdx.x == 0) {
        int t = threadIdx.x;
        int val = (t < nch) ? bsum[t] : 0;
        sh[t] = val;
        __syncthreads();
        for (int o = 1; o < 256; o <<= 1) {
            int x = (t >= o) ? sh[t - o] : 0;
            __syncthreads();
            sh[t] += x;
            __syncthreads();
        }
        if (t < nch) bsum[t] = sh[t] - val;
    }
    g.sync();

    // phase 4: add chunk prefixes; init cursor
    for (int i = tid; i <= n; i += nth) {
        int o = offs[i] + bsum[i >> 8];
        offs[i] = o;
        if (i < n) counts[i] = o;  // cursor
    }
    g.sync();

    // phase 5: scatter into packed CSR (src low16, bf16 wgt high16)
    for (int e = tid; e < E; e += nth) {
        int d = fi ? eix[2 * (E + e)] : eix[E + e];
        int s = fi ? eix[2 * e] : eix[e];
        int pos = atomicAdd(&counts[d], 1);
        unsigned short wb = ff ? f_to_u16bf(((const float*)ewp)[e])
                               : ((const unsigned short*)ewp)[e];
        csr[pos] = (unsigned)(s & 0xFFFF) | ((unsigned)wb << 16);
    }
}

// ---------------- K3: layer-1 agg + residual + LN -> h1 (in d_out) ----------------
// one wave/node; leaky(x)=0.6x+0.4|x| folded into dot; self-loop hoisted; x4 unroll
__global__ void __launch_bounds__(256) k_agg1(
    const int* __restrict__ nid, const int* __restrict__ offs,
    const unsigned* __restrict__ csr,
    const float* __restrict__ EWl, const float* __restrict__ EWr,
    const float* __restrict__ emb,
    const float* __restrict__ We, const float* __restrict__ att,
    const float* __restrict__ bias, const float* __restrict__ g, const float* __restrict__ be,
    const float* __restrict__ ew_sum, float invE, int n,
    const int* __restrict__ flagf, const int* __restrict__ flagi,
    void* __restrict__ h1) {
    int v = (int)(((long)blockIdx.x * blockDim.x + threadIdx.x) >> 6);
    int lane = threadIdx.x & 63;
    if (v >= n) return;
    int fi = *flagi;
    int tv = fi ? nid[2 * v] : nid[v];
    const float2* L = (const float2*)EWl;
    const float2* R = (const float2*)EWr;
    float2 xr = R[tv * 64 + lane];
    int c0 = 2 * lane, c1 = c0 + 1;
    float wex = We[c0], wey = We[c1];
    float ax = att[c0], ay = att[c1];
    float ux = 0.6f * ax, uy = 0.6f * ay;
    float qx = 0.4f * ax, qy = 0.4f * ay;
    float wmean = ew_sum[0] * invE;

    // self loop
    float2 xls = L[tv * 64 + lane];
    float mx = xls.x + fmaf(wmean, wex, xr.x);
    float my = xls.y + fmaf(wmean, wey, xr.y);
    float ps = fmaf(ux, mx, fmaf(qx, fabsf(mx), fmaf(uy, my, qy * fabsf(my))));
    for (int o = 1; o < 64; o <<= 1) ps += __shfl_xor(ps, o, 64);
    float ev0 = __expf(ps);
    float den = ev0, accx = ev0 * xls.x, accy = ev0 * xls.y;

    int e0 = offs[v];
    int deg = offs[v + 1] - e0;
    for (int base = 0; base < deg; base += 4) {
        float p[4], lx[4], ly[4];
#pragma unroll
        for (int j = 0; j < 4; ++j) {
            int idx = base + j;
            int ce = e0 + (idx < deg ? idx : deg - 1);
            unsigned pk = csr[ce];
            int s = (int)(pk & 0xFFFFu);
            float w = __uint_as_float(pk & 0xFFFF0000u);
            int ts = fi ? nid[2 * s] : nid[s];
            float2 xl = L[ts * 64 + lane];
            lx[j] = xl.x;
            ly[j] = xl.y;
            float mjx = xl.x + fmaf(w, wex, xr.x);
            float mjy = xl.y + fmaf(w, wey, xr.y);
            p[j] = fmaf(ux, mjx, fmaf(qx, fabsf(mjx), fmaf(uy, mjy, qy * fabsf(mjy))));
        }
#pragma unroll
        for (int o = 1; o < 64; o <<= 1) {
#pragma unroll
            for (int j = 0; j < 4; ++j) p[j] += __shfl_xor(p[j], o, 64);
        }
#pragma unroll
        for (int j = 0; j < 4; ++j) {
            float ev = (base + j < deg) ? __expf(p[j]) : 0.f;
            den += ev;
            accx = fmaf(ev, lx[j], accx);
            accy = fmaf(ev, ly[j], accy);
        }
    }
    float inv = 1.f / den;
    const float2* emb2 = (const float2*)emb;
    float2 res = emb2[tv * 64 + lane];
    float vx = fmaf(accx, inv, bias[c0] + res.x);
    float vy = fmaf(accy, inv, bias[c1] + res.y);
    float s1 = vx + vy;
    for (int o = 1; o < 64; o <<= 1) s1 += __shfl_xor(s1, o, 64);
    float mu = s1 * (1.f / 128.f);
    float dx = vx - mu, dy = vy - mu;
    float s2 = dx * dx + dy * dy;
    for (int o = 1; o < 64; o <<= 1) s2 += __shfl_xor(s2, o, 64);
    float rstd = rsqrtf(s2 * (1.f / 128.f) + 1e-5f);
    float ox = fmaf(dx * rstd, g[c0], be[c0]);
    float oy = fmaf(dy * rstd, g[c1], be[c1]);
    if (*flagf) {
        ((float2*)h1)[(long)v * 64 + lane] = make_float2(ox, oy);
    } else {
        __hip_bfloat162 hb;
        hb.x = __float2bfloat16(ox);
        hb.y = __float2bfloat16(oy);
        ((__hip_bfloat162*)h1)[(long)v * 64 + lane] = hb;
    }
}

// ---------------- K4: layer-2 GEMMs via MFMA: xl2 = h1@W2l + b2l, xr2 = h1@W2r + b2r ----------------
// one wave per 16-row tile; W2 pre-transposed [n][k] bf16; A loaded 16B/lane from h1 rows.
__global__ void __launch_bounds__(256) k_gemm2(
    const void* __restrict__ h1, const int* __restrict__ flagf,
    const unsigned short* __restrict__ w2lT, const unsigned short* __restrict__ w2rT,
    const float* __restrict__ b2l, const float* __restrict__ b2r, int n,
    bf16* __restrict__ xl2, bf16* __restrict__ xr2) {
    int wave = (int)(((long)blockIdx.x * blockDim.x + threadIdx.x) >> 6);
    int lane = threadIdx.x & 63;
    int row0 = wave * 16;
    if (row0 >= n) return;
    int ff = *flagf;
    int m = lane & 15, quad = lane >> 4;

    short8 a[4];
    long rbase = (long)(row0 + m) * D;
    if (ff) {
        const float* hf = (const float*)h1;
#pragma unroll
        for (int ks = 0; ks < 4; ++ks) {
            int k0 = ks * 32 + quad * 8;
            short8 t;
#pragma unroll
            for (int j = 0; j < 8; ++j) t[j] = (short)f_to_u16bf(hf[rbase + k0 + j]);
            a[ks] = t;
        }
    } else {
        const unsigned short* hb = (const unsigned short*)h1;
#pragma unroll
        for (int ks = 0; ks < 4; ++ks) {
            int k0 = ks * 32 + quad * 8;
            a[ks] = *(const short8*)(hb + rbase + k0);
        }
    }
#pragma unroll
    for (int nt = 0; nt < 8; ++nt) {
        int ncol = nt * 16 + m;
        float4v accl = {0.f, 0.f, 0.f, 0.f};
        float4v accr = {0.f, 0.f, 0.f, 0.f};
        long bbase = (long)ncol * D + quad * 8;
#pragma unroll
        for (int ks = 0; ks < 4; ++ks) {
            short8 bl = *(const short8*)(w2lT + bbase + ks * 32);
            short8 br = *(const short8*)(w2rT + bbase + ks * 32);
            accl = __builtin_amdgcn_mfma_f32_16x16x32_bf16(a[ks], bl, accl, 0, 0, 0);
            accr = __builtin_amdgcn_mfma_f32_16x16x32_bf16(a[ks], br, accr, 0, 0, 0);
        }
        float bll = b2l[ncol], brr = b2r[ncol];
#pragma unroll
        for (int r = 0; r < 4; ++r) {
            long row = row0 + quad * 4 + r;
            xl2[row * D + ncol] = __float2bfloat16(accl[r] + bll);
            xr2[row * D + ncol] = __float2bfloat16(accr[r] + brr);
        }
    }
}

// ---------------- K5: layer-2 agg + residual + LN -> out. h1 aliases out. ----------------
__global__ void __launch_bounds__(256) k_agg2(
    const int* __restrict__ offs, const unsigned* __restrict__ csr,
    const bf16* __restrict__ xl2, const bf16* __restrict__ xr2,
    const void* h1,
    const float* __restrict__ We, const float* __restrict__ att,
    const float* __restrict__ bias, const float* __restrict__ g, const float* __restrict__ be,
    const float* __restrict__ ew_sum, float invE, int n,
    const int* __restrict__ flagf, void* out) {
    int v = (int)(((long)blockIdx.x * blockDim.x + threadIdx.x) >> 6);
    int lane = threadIdx.x & 63;
    if (v >= n) return;
    int ff = *flagf;
    int c0 = 2 * lane, c1 = c0 + 1;
    float resx, resy;
    if (ff) {
        float2 rb = ((const float2*)h1)[(long)v * 64 + lane];
        resx = rb.x; resy = rb.y;
    } else {
        __hip_bfloat162 rb = ((const __hip_bfloat162*)h1)[(long)v * 64 + lane];
        resx = bf2f(rb.x); resy = bf2f(rb.y);
    }
    const __hip_bfloat162* L = (const __hip_bfloat162*)xl2;
    const __hip_bfloat162* R = (const __hip_bfloat162*)xr2;
    __hip_bfloat162 xrb = R[(long)v * 64 + lane];
    float xrx = bf2f(xrb.x), xry = bf2f(xrb.y);
    float wex = We[c0], wey = We[c1];
    float ax = att[c0], ay = att[c1];
    float ux = 0.6f * ax, uy = 0.6f * ay;
    float qx = 0.4f * ax, qy = 0.4f * ay;
    float wmean = ew_sum[0] * invE;

    // self loop
    __hip_bfloat162 xsb = L[(long)v * 64 + lane];
    float sx = bf2f(xsb.x), sy = bf2f(xsb.y);
    float mx = sx + fmaf(wmean, wex, xrx);
    float my = sy + fmaf(wmean, wey, xry);
    float ps = fmaf(ux, mx, fmaf(qx, fabsf(mx), fmaf(uy, my, qy * fabsf(my))));
    for (int o = 1; o < 64; o <<= 1) ps += __shfl_xor(ps, o, 64);
    float ev0 = __expf(ps);
    float den = ev0, accx = ev0 * sx, accy = ev0 * sy;

    int e0 = offs[v];
    int deg = offs[v + 1] - e0;
    for (int base = 0; base < deg; base += 4) {
        float p[4], lx[4], ly[4];
#pragma unroll
        for (int j = 0; j < 4; ++j) {
            int idx = base + j;
            int ce = e0 + (idx < deg ? idx : deg - 1);
            unsigned pk = csr[ce];
            int s = (int)(pk & 0xFFFFu);
            float w = __uint_as_float(pk & 0xFFFF0000u);
            __hip_bfloat162 xlb = L[(long)s * 64 + lane];
            lx[j] = bf2f(xlb.x);
            ly[j] = bf2f(xlb.y);
            float mjx = lx[j] + fmaf(w, wex, xrx);
            float mjy = ly[j] + fmaf(w, wey, xry);
            p[j] = fmaf(ux, mjx, fmaf(qx, fabsf(mjx), fmaf(uy, mjy, qy * fabsf(mjy))));
        }
#pragma unroll
        for (int o = 1; o < 64; o <<= 1) {
#pragma unroll
            for (int j = 0; j < 4; ++j) p[j] += __shfl_xor(p[j], o, 64);
        }
#pragma unroll
        for (int j = 0; j < 4; ++j) {
            float ev = (base + j < deg) ? __expf(p[j]) : 0.f;
            den += ev;
            accx = fmaf(ev, lx[j], accx);
            accy = fmaf(ev, ly[j], accy);
        }
    }
    float inv = 1.f / den;
    float vx = fmaf(accx, inv, bias[c0] + resx);
    float vy = fmaf(accy, inv, bias[c1] + resy);
    float s1 = vx + vy;
    for (int o = 1; o < 64; o <<= 1) s1 += __shfl_xor(s1, o, 64);
    float mu = s1 * (1.f / 128.f);
    float dx = vx - mu, dy = vy - mu;
    float s2 = dx * dx + dy * dy;
    for (int o = 1; o < 64; o <<= 1) s2 += __shfl_xor(s2, o, 64);
    float rstd = rsqrtf(s2 * (1.f / 128.f) + 1e-5f);
    float ox = fmaf(dx * rstd, g[c0], be[c0]);
    float oy = fmaf(dy * rstd, g[c1], be[c1]);
    if (ff) {
        ((float2*)out)[(long)v * 64 + lane] = make_float2(ox, oy);
    } else {
        __hip_bfloat162 ob;
        ob.x = __float2bfloat16(ox);
        ob.y = __float2bfloat16(oy);
        ((__hip_bfloat162*)out)[(long)v * 64 + lane] = ob;
    }
}

extern "C" void kernel_launch(void* const* d_in, const int* in_sizes, int n_in,
                              void* d_out, int out_size, void* d_ws, size_t ws_size,
                              hipStream_t stream) {
    const int n = in_sizes[0];
    int E = in_sizes[1] / 2;
    const int* nid = (const int*)d_in[0];
    const int* eix = (const int*)d_in[1];
    const void* ew = d_in[2];

    char* base = (char*)d_ws;
    size_t off = 0;
    auto alloc = [&](size_t bytes) -> char* {
        size_t o = (off + 15) & ~(size_t)15;
        off = o + bytes;
        return base + o;
    };
    int*   flagf  = (int*)alloc(4);
    int*   flagi  = (int*)alloc(4);
    float* ew_sum = (float*)alloc(4);
    float* EWl    = (float*)alloc((size_t)D * D * 4);
    float* EWr    = (float*)alloc((size_t)D * D * 4);
    unsigned short* w2lT = (unsigned short*)alloc((size_t)D * D * 2);
    unsigned short* w2rT = (unsigned short*)alloc((size_t)D * D * 2);
    int*   offs     = (int*)alloc((size_t)(n + 1) * 4);
    int*   countcur = (int*)alloc((size_t)n * 4);
    int*   bsum     = (int*)alloc(256 * 4);
    unsigned* csr   = (unsigned*)alloc((size_t)E * 4);
    bf16*  xl2    = (bf16*)alloc((size_t)n * D * 2);
    bf16*  xr2    = (bf16*)alloc((size_t)n * D * 2);

    CvArgs cv;
    float* P[NCV];
    for (int i = 0; i < NCV; ++i) {
        int sz = in_sizes[3 + i];
        P[i] = (float*)alloc((size_t)sz * 4);
        cv.s[i] = d_in[3 + i];
        cv.d[i] = P[i];
        cv.n[i] = sz;
    }
    float* emb_f = P[0];
    float* w1e = P[5], *att1 = P[6], *bias1 = P[7], *g1 = P[8], *be1 = P[9];
    float* b2l = P[11], *b2r = P[13];
    float* w2e = P[14], *att2 = P[15], *bias2 = P[16], *g2 = P[17], *be2 = P[18];

    void* h1 = d_out;
    const float invE = 1.0f / (float)E;

    // 1) prep: flags + conversions + vocab tables + W2 transposes
    k_prep<<<85, 256, 0, stream>>>(cv, eix, EWl, EWr, w2lT, w2rT, flagf, flagi);

    // 2) cooperative CSR build
    {
        void* args[] = {(void*)&eix, (void*)&ew, (void*)&E, (void*)&n,
                        (void*)&flagf, (void*)&flagi, (void*)&countcur, (void*)&offs,
                        (void*)&bsum, (void*)&csr, (void*)&ew_sum};
        hipLaunchCooperativeKernel((void*)k_csr, dim3(224), dim3(256), args, 0, stream);
    }

    // 3) layer-1 fused agg + LN
    k_agg1<<<(n + 3) / 4, 256, 0, stream>>>(nid, offs, csr, EWl, EWr, emb_f,
                                            w1e, att1, bias1, g1, be1,
                                            ew_sum, invE, n, flagf, flagi, h1);
    // 4) layer-2 GEMMs (MFMA)
    {
        int waves = (n + 15) / 16;
        int blocks = (waves + 3) / 4;
        k_gemm2<<<blocks, 256, 0, stream>>>(h1, flagf, w2lT, w2rT, b2l, b2r, n, xl2, xr2);
    }
    // 5) layer-2 fused agg + LN
    k_agg2<<<(n + 3) / 4, 256, 0, stream>>>(offs, csr, xl2, xr2, h1,
                                            w2e, att2, bias2, g2, be2,
                                            ew_sum, invE, n, flagf, d_out);
}